// Round 10
// baseline (163.152 us; speedup 1.0000x reference)
//
#include <hip/hip_runtime.h>

#define BATCH 256
#define SEQ 2048
#define NT 48
#define START_TAG 46
#define END_TAG 47
#define LN2f  0.6931471805599453f
#define LOG2E 1.4426950408889634f

// ws layout
#define TAF 0          // A-frags of exp(trans) bf16: [9][64] x 8B   (4608 B)
#define TBF 4608       // B-frag exp(trans) f32:      [9][64] x 16B  (9216 B)
#define TSC 16384      // per-chunk log2 scales: [B][NCH] f32        (<=64 KiB)
#define TW  131072     // chunk matrices M^T bf16: [B][NCH][48][48]

typedef float v2f __attribute__((ext_vector_type(2)));
typedef float v4f __attribute__((ext_vector_type(4)));
typedef short s16x4 __attribute__((ext_vector_type(4)));
typedef unsigned int u32;
typedef u32 u32x2 __attribute__((ext_vector_type(2)));
typedef u32 u32x4 __attribute__((ext_vector_type(4)));

__device__ __forceinline__ u32 pkbf(float a, float b) {
    u32 r;
    asm("v_cvt_pk_bf16_f32 %0, %1, %2" : "=v"(r) : "v"(a), "v"(b));
    return r;
}

__device__ __forceinline__ float rfl(float x) {
    return __builtin_bit_cast(float,
        __builtin_amdgcn_readfirstlane(__builtin_bit_cast(int, x)));
}

// Inline-asm MFMA (VGPR accs, order pinned).  Level-0 uses early-clobber
// (dst must not alias SrcA/SrcB); accumulate form is in-place dst==SrcC.
__device__ __forceinline__ v4f mfma16_z(s16x4 a, s16x4 b, v4f z) {
    v4f d;
    asm volatile("v_mfma_f32_16x16x16_bf16 %0, %2, %3, %1"
                 : "=&v"(d) : "v"(z), "v"(a), "v"(b));
    return d;
}
__device__ __forceinline__ void mfma16_acc(v4f& acc, s16x4 a, s16x4 b) {
    asm volatile("v_mfma_f32_16x16x16_bf16 %0, %1, %2, %0"
                 : "+v"(acc) : "v"(a), "v"(b));
}

__device__ __forceinline__ void mfma_level0(v4f (&acc)[3][3],
                                            const s16x4 (&aw)[3][3],
                                            const s16x4 (&mw)[3][3],
                                            const v4f kz) {
    #pragma unroll
    for (int I = 0; I < 3; ++I)
        #pragma unroll
        for (int J = 0; J < 3; ++J)
            acc[I][J] = mfma16_z(aw[I][0], mw[0][J], kz);
}
template<int K>
__device__ __forceinline__ void mfma_level(v4f (&acc)[3][3],
                                           const s16x4 (&aw)[3][3],
                                           const s16x4 (&mw)[3][3]) {
    #pragma unroll
    for (int I = 0; I < 3; ++I)
        #pragma unroll
        for (int J = 0; J < 3; ++J)
            mfma16_acc(acc[I][J], aw[I][K], mw[K][J]);
}

// fold: mw = bf16( acc[K][J] * (em[K] * s) )
__device__ __forceinline__ void scale_fold(s16x4 (&mw)[3][3],
                                           const v4f (&acc)[3][3],
                                           const v4f (&em)[3], float s) {
    #pragma unroll
    for (int K = 0; K < 3; ++K) {
        v4f sp = em[K] * s;
        #pragma unroll
        for (int J = 0; J < 3; ++J) {
            v4f sc = acc[K][J] * sp;
            mw[K][J] = __builtin_bit_cast(s16x4,
                (u32x2){pkbf(sc.x, sc.y), pkbf(sc.z, sc.w)});
        }
    }
}

// ---------------------------------------------------------------------------
// Kernel 0: build exp(trans) fragments once. 1 block x 64.
// A-frag (tile I,K): lane holds E[I*16+(l&15)][K*16+(l>>4)*4+i], i=0..3, bf16.
// B-frag (tile K,J): lane holds E[K*16+(l>>4)*4+i][J*16+(l&15)], f32.
// ---------------------------------------------------------------------------
__global__ void __launch_bounds__(64)
crf_setup(const float* __restrict__ trans, void* ws) {
    __shared__ float el[NT * NT];
    const int lane = threadIdx.x, ln = lane & 15, g = lane >> 4;
    #pragma unroll
    for (int m = 0; m < 36; ++m) {
        int idx = lane + 64 * m;
        el[idx] = __expf(trans[idx]);
    }
    u32x2* AF = (u32x2*)((char*)ws + TAF);
    v4f*   BF = (v4f*)((char*)ws + TBF);
    #pragma unroll
    for (int I = 0; I < 3; ++I)
        #pragma unroll
        for (int K = 0; K < 3; ++K) {
            const v4f ev = *(const v4f*)&el[(I * 16 + ln) * NT + K * 16 + g * 4];
            u32x2 w;
            w.x = pkbf(ev.x, ev.y);
            w.y = pkbf(ev.z, ev.w);
            AF[(I * 3 + K) * 64 + lane] = w;
        }
    #pragma unroll
    for (int K = 0; K < 3; ++K)
        #pragma unroll
        for (int J = 0; J < 3; ++J) {
            v4f v;
            #pragma unroll
            for (int i = 0; i < 4; ++i)
                v[i] = el[(K * 16 + g * 4 + i) * NT + J * 16 + ln];
            BF[(K * 3 + J) * 64 + lane] = v;
        }
}

// ---------------------------------------------------------------------------
// Kernel 1 (dual): each wave owns TWO chunks (2w, 2w+1), 32 steps each,
// chains interleaved at MFMA-level granularity (A0,B0,A1,B1,A2,B2) so the
// in-order wave never stalls on its own MFMA latency.  Emissions for both
// chunks (64 contiguous rows) are exp()'d ONCE at staging into LDS; per step
// the rescale is sp = em * (1/gn_prev) (rcp, no exp2 on the path).
// Partial B (nB < 32) exits to a branch-free A-only tail loop; nB is
// wave-uniform so the split is scalar-branch only.
// Round 4-9 lesson: per-CU pipe math showed MFMA+VALU both issue at full
// rate; the limiter was per-wave latency x too few chains/CU.  This kernel
// doubles chains per wave and triples waves per CU (48KB LDS/WG, ~170 VGPR).
// ---------------------------------------------------------------------------
__global__ void __launch_bounds__(256, 2)
crf_phase1_dual(const float* __restrict__ feat, const int* __restrict__ seqlen,
                void* __restrict__ ws) {
    const int b = blockIdx.x;
    const int wid = threadIdx.x >> 6;
    const int w = blockIdx.y * 4 + wid;          // pair index 0..31
    const int t0 = w * 64;
    const int L = seqlen[b];
    int nA = L - t0;
    if (nA <= 0) return;
    if (nA > 32) nA = 32;
    int nB = L - t0 - 32;
    if (nB < 0) nB = 0;
    if (nB > 32) nB = 32;

    const int lane = threadIdx.x & 63, ln = lane & 15, g = lane >> 4;

    __shared__ v4f flv[4][768];      // per-wave: 64 rows x 12 v4f (exp'd), 12KB
    v4f* fl = flv[wid];

    const u32x2* AF = (const u32x2*)((const char*)ws + TAF);
    const v4f*   BF = (const v4f*)((const char*)ws + TBF);

    s16x4 aw[3][3];
    #pragma unroll
    for (int I = 0; I < 3; ++I)
        #pragma unroll
        for (int K = 0; K < 3; ++K)
            aw[I][K] = __builtin_bit_cast(s16x4, AF[(I * 3 + K) * 64 + lane]);

    // stage rows t0..t0+63 (always in-bounds: t0 <= 1984), exp() applied once
    {
        const v4f* fg = (const v4f*)(feat + ((size_t)b * SEQ + t0) * NT);
        #pragma unroll
        for (int m = 0; m < 12; ++m) {
            v4f v = fg[m * 64 + lane];
            v4f e;
            #pragma unroll
            for (int i = 0; i < 4; ++i) e[i] = __expf(v[i]);
            fl[m * 64 + lane] = e;
        }
    }

    const v4f kz = {0.f, 0.f, 0.f, 0.f};

    // init M = D_{t0} E for both chains (emissions already exp'd in LDS)
    s16x4 mwA[3][3], mwB[3][3];
    {
        v4f emx[3];
        #pragma unroll
        for (int K = 0; K < 3; ++K) emx[K] = fl[K * 4 + g];
        #pragma unroll
        for (int K = 0; K < 3; ++K)
            #pragma unroll
            for (int J = 0; J < 3; ++J) {
                v4f sc = BF[(K * 3 + J) * 64 + lane] * emx[K];
                mwA[K][J] = __builtin_bit_cast(s16x4,
                    (u32x2){pkbf(sc.x, sc.y), pkbf(sc.z, sc.w)});
            }
    }
    if (nB > 0) {
        v4f emx[3];
        #pragma unroll
        for (int K = 0; K < 3; ++K) emx[K] = fl[32 * 12 + K * 4 + g];
        #pragma unroll
        for (int K = 0; K < 3; ++K)
            #pragma unroll
            for (int J = 0; J < 3; ++J) {
                v4f sc = BF[(K * 3 + J) * 64 + lane] * emx[K];
                mwB[K][J] = __builtin_bit_cast(s16x4,
                    (u32x2){pkbf(sc.x, sc.y), pkbf(sc.z, sc.w)});
            }
    }

    float LcA = 0.f, lgA = 0.f, sA = 1.f;
    float LcB = 0.f, lgB = 0.f, sB = 1.f;

    int t = 1;
    // ---- dual loop: t = 1..nB-1 (nB>0 implies nA==32, so A is full)
    for (; t < nB; ++t) {
        v4f emA[3], emB[3];
        #pragma unroll
        for (int K = 0; K < 3; ++K) emA[K] = fl[t * 12 + K * 4 + g];
        #pragma unroll
        for (int K = 0; K < 3; ++K) emB[K] = fl[(32 + t) * 12 + K * 4 + g];

        v4f accA[3][3], accB[3][3];
        mfma_level0(accA, aw, mwA, kz);
        mfma_level0(accB, aw, mwB, kz);
        mfma_level<1>(accA, aw, mwA);
        mfma_level<1>(accB, aw, mwB);
        mfma_level<2>(accA, aw, mwA);
        mfma_level<2>(accB, aw, mwB);
        asm volatile("s_nop 7\n\ts_nop 7");
        __builtin_amdgcn_sched_barrier(0);

        const float gnA = rfl(accA[0][0].x);
        const float gnB = rfl(accB[0][0].x);
        LcA += lgA;
        scale_fold(mwA, accA, emA, sA);
        lgA = __log2f(gnA);
        sA = __builtin_amdgcn_rcpf(gnA);
        LcB += lgB;
        scale_fold(mwB, accB, emB, sB);
        lgB = __log2f(gnB);
        sB = __builtin_amdgcn_rcpf(gnB);
    }
    // ---- A-only tail: t = max(1,nB)..nA-1
    for (; t < nA; ++t) {
        v4f emA[3];
        #pragma unroll
        for (int K = 0; K < 3; ++K) emA[K] = fl[t * 12 + K * 4 + g];

        v4f accA[3][3];
        mfma_level0(accA, aw, mwA, kz);
        mfma_level<1>(accA, aw, mwA);
        mfma_level<2>(accA, aw, mwA);
        asm volatile("s_nop 7\n\ts_nop 7");
        __builtin_amdgcn_sched_barrier(0);

        const float gnA = rfl(accA[0][0].x);
        LcA += lgA;
        scale_fold(mwA, accA, emA, sA);
        lgA = __log2f(gnA);
        sA = __builtin_amdgcn_rcpf(gnA);
    }

    // ---- store M^T bf16 (element M[kk][nn] -> byte 2*(nn*48+kk)) + scales
    {
        const int cA = 2 * w;
        char* wb = (char*)ws + TW + ((size_t)(b * 64 + cA)) * 4608;
        #pragma unroll
        for (int K = 0; K < 3; ++K)
            #pragma unroll
            for (int J = 0; J < 3; ++J) {
                u32x2 wv = __builtin_bit_cast(u32x2, mwA[K][J]);
                *(u32*)(wb + 2 * ((J * 16 + ln) * NT + K * 16 + g * 4))     = wv.x;
                *(u32*)(wb + 2 * ((J * 16 + ln) * NT + K * 16 + g * 4 + 2)) = wv.y;
            }
        if (lane == 0)
            ((float*)((char*)ws + TSC))[b * 64 + cA] = LcA;
    }
    if (nB > 0) {
        const int cB = 2 * w + 1;
        char* wb = (char*)ws + TW + ((size_t)(b * 64 + cB)) * 4608;
        #pragma unroll
        for (int K = 0; K < 3; ++K)
            #pragma unroll
            for (int J = 0; J < 3; ++J) {
                u32x2 wv = __builtin_bit_cast(u32x2, mwB[K][J]);
                *(u32*)(wb + 2 * ((J * 16 + ln) * NT + K * 16 + g * 4))     = wv.x;
                *(u32*)(wb + 2 * ((J * 16 + ln) * NT + K * 16 + g * 4 + 2)) = wv.y;
            }
        if (lane == 0)
            ((float*)((char*)ws + TSC))[b * 64 + cB] = LcB;
    }
}

// ---------------------------------------------------------------------------
// Kernel 2: per sample, u^T <- u^T * M_c for c = nb-1..0; lane j owns u[j];
// M^T row j contiguous bf16; next chunk's row double-buffered.
// ---------------------------------------------------------------------------
template<int LCH_, int NCH_>
__global__ void __launch_bounds__(64)
crf_phase2(const float* __restrict__ trans, const int* __restrict__ seqlen,
           const void* __restrict__ ws, float* __restrict__ out) {
    const int b = blockIdx.x;
    const int lane = threadIdx.x;
    const int j = (lane < NT) ? lane : (lane - 16);
    __shared__ v4f hs4[12];
    float* hs = (float*)hs4;

    const int L = seqlen[b];
    const int nb = (L + LCH_ - 1) / LCH_;
    const float* sc = (const float*)((const char*)ws + TSC) + b * NCH_;
    const char* wbase = (const char*)ws + TW + (size_t)b * NCH_ * 4608;

    float q = __expf(trans[END_TAG * NT + j]);   // u0 (exp(MIN)=0 -> col END)
    float D = 0.f;

    u32x4 buf[6];
    {
        const u32x4* wr = (const u32x4*)(wbase + (size_t)(nb - 1) * 4608 + j * 96);
        #pragma unroll
        for (int m = 0; m < 6; ++m) buf[m] = wr[m];
    }

    for (int c = nb - 1; c >= 0; --c) {
        u32x4 cur[6];
        #pragma unroll
        for (int m = 0; m < 6; ++m) cur[m] = buf[m];
        if (c > 0) {
            const u32x4* wr = (const u32x4*)(wbase + (size_t)(c - 1) * 4608 + j * 96);
            #pragma unroll
            for (int m = 0; m < 6; ++m) buf[m] = wr[m];
        }

        if (lane < NT) hs[lane] = q;
        v4f hq[12];
        #pragma unroll
        for (int k = 0; k < 12; ++k) hq[k] = hs4[k];
        const float h0 = hq[0][0];

        v2f a = {0.f, 0.f};
        #pragma unroll
        for (int m = 0; m < 6; ++m) {
            #pragma unroll
            for (int p = 0; p < 4; ++p) {
                const int i = 2 * (4 * m + p);
                u32 wv = cur[m][p];
                v2f wp;
                wp.x = __builtin_bit_cast(float, wv << 16);
                wp.y = __builtin_bit_cast(float, wv & 0xffff0000u);
                v2f up = { hq[i >> 2][i & 3], hq[i >> 2][(i & 3) + 1] };
                a += wp * up;
            }
        }
        const float dot = a.x + a.y;
        q = dot * __builtin_amdgcn_rcpf(h0);
        D += __log2f(h0) + sc[c];
    }
    if (lane < NT) hs[lane] = q;
    if (lane == 0)
        out[b] = LN2f * (D + __log2f(hs[START_TAG]));
}

// ---------------------------------------------------------------------------
// Fallback: proven round-2 scalar kernel (ws too small)
// ---------------------------------------------------------------------------
__global__ void __launch_bounds__(64)
crf_scalar(const float* __restrict__ features, const float* __restrict__ transitions,
           const int* __restrict__ seq_len, float* __restrict__ out) {
    const int b = blockIdx.x;
    const int lane = threadIdx.x;
    const int j = (lane < NT) ? lane : (lane - 16);
    __shared__ v4f hs4[NT / 4];
    float* hs = (float*)hs4;

    v2f E2[NT / 2];
    {
        const v4f* trow = (const v4f*)(transitions + j * NT);
        #pragma unroll
        for (int k = 0; k < NT / 4; ++k) {
            v4f tv = trow[k];
            E2[2 * k].x = __expf(tv.x); E2[2 * k].y = __expf(tv.y);
            E2[2 * k + 1].x = __expf(tv.z); E2[2 * k + 1].y = __expf(tv.w);
        }
    }
    const float Eend = __expf(transitions[END_TAG * NT + j]);
    const int L = seq_len[b];
    const float* fbase = features + ((size_t)b * SEQ) * NT + j;

    float q = E2[START_TAG / 2].x * __expf(fbase[0]);
    float Clog2 = 0.0f;
    if (lane < NT) hs[lane] = q;

    float fb[8];
    #pragma unroll
    for (int u = 0; u < 8; ++u) {
        int tp = 1 + u;
        fb[u] = fbase[(size_t)(tp < SEQ ? tp : 0) * NT];
    }

    auto STEP = [&](float femit) {
        v4f hq[NT / 4];
        #pragma unroll
        for (int k = 0; k < NT / 4; ++k) hq[k] = hs4[k];
        float h0 = hq[0].x;
        float r = __builtin_amdgcn_rcpf(h0);
        float e = __expf(femit);
        float re = r * e;
        v2f a0 = {0.f, 0.f}, a1 = {0.f, 0.f};
        #pragma unroll
        for (int k = 0; k < NT / 4; ++k) {
            v2f lo = { hq[k].x, hq[k].y };
            v2f hi = { hq[k].z, hq[k].w };
            a0 += E2[2 * k] * lo;
            a1 += E2[2 * k + 1] * hi;
        }
        float d = (a0.x + a1.x) + (a0.y + a1.y);
        q = d * re;
        Clog2 += __log2f(h0);
        if (lane < NT) hs[lane] = q;
    };

    int t = 1;
    while (t + 8 <= L) {
        #pragma unroll
        for (int u = 0; u < 8; ++u) {
            STEP(fb[u]);
            int tp = t + u + 8;
            fb[u] = fbase[(size_t)(tp < SEQ ? tp : 0) * NT];
        }
        t += 8;
    }
    #pragma unroll
    for (int u = 0; u < 8; ++u)
        if (t + u < L) STEP(fb[u]);

    float term = (lane < NT) ? q * Eend : 0.0f;
    #pragma unroll
    for (int m = 32; m >= 1; m >>= 1) term += __shfl_xor(term, m, 64);
    if (lane == 0) out[b] = LN2f * (Clog2 + __log2f(term));
}

extern "C" void kernel_launch(void* const* d_in, const int* in_sizes, int n_in,
                              void* d_out, int out_size, void* d_ws, size_t ws_size,
                              hipStream_t stream) {
    const float* features    = (const float*)d_in[0];
    const float* transitions = (const float*)d_in[1];
    const int*   seqlen      = (const int*)d_in[2];
    float* out = (float*)d_out;

    const size_t need64 = (size_t)TW + (size_t)BATCH * 64 * 4608;   // ~75.6 MB
    if (ws_size >= need64) {
        crf_setup<<<1, 64, 0, stream>>>(transitions, d_ws);
        crf_phase1_dual<<<dim3(BATCH, 8), 256, 0, stream>>>(features, seqlen, d_ws);
        crf_phase2<32, 64><<<BATCH, 64, 0, stream>>>(transitions, seqlen, d_ws, out);
    } else {
        crf_scalar<<<BATCH, 64, 0, stream>>>(features, transitions, seqlen, out);
    }
}

// Round 12
// 157.498 us; speedup vs baseline: 1.0359x; 1.0359x over previous
//
#include <hip/hip_runtime.h>

#define BATCH 256
#define SEQ 2048
#define NT 48
#define START_TAG 46
#define END_TAG 47
#define LN2f  0.6931471805599453f

// ws layout
#define TAF16 0        // K16 A-frags exp(trans) bf16: [9][64] x 8B  = 4608
#define TAF32 4608     // K32 A-frags: [3 I][2 Kc][64] x 16B         = 6144
#define TBF   10752    // B-frag exp(trans) f32: [9][64] x 16B       = 9216
#define TFLAG 19968    // u32: 1 = K32 path validated on this HW
#define TSC   20480    // per-chunk log2 scales: [B][64] f32         = 65536
#define TW    131072   // chunk matrices M^T bf16: [B][64][48][48]

typedef float v2f __attribute__((ext_vector_type(2)));
typedef float v4f __attribute__((ext_vector_type(4)));
typedef short s16x4 __attribute__((ext_vector_type(4)));
typedef short s16x8 __attribute__((ext_vector_type(8)));
typedef unsigned int u32;
typedef u32 u32x2 __attribute__((ext_vector_type(2)));
typedef u32 u32x4 __attribute__((ext_vector_type(4)));

__device__ __forceinline__ u32 pkbf(float a, float b) {
    u32 r;
    asm("v_cvt_pk_bf16_f32 %0, %1, %2" : "=v"(r) : "v"(a), "v"(b));
    return r;
}
__device__ __forceinline__ float bflo(u32 w) { return __builtin_bit_cast(float, w << 16); }
__device__ __forceinline__ float bfhi(u32 w) { return __builtin_bit_cast(float, w & 0xffff0000u); }

__device__ __forceinline__ float rfl(float x) {
    return __builtin_bit_cast(float,
        __builtin_amdgcn_readfirstlane(__builtin_bit_cast(int, x)));
}

// ---- inline-asm MFMAs (order pinned; dst==srcC legal for acc form) ----
__device__ __forceinline__ v4f mfma16_z(s16x4 a, s16x4 b, v4f z) {
    v4f d;
    asm volatile("v_mfma_f32_16x16x16_bf16 %0, %2, %3, %1"
                 : "=&v"(d) : "v"(z), "v"(a), "v"(b));
    return d;
}
__device__ __forceinline__ void mfma16_acc(v4f& acc, s16x4 a, s16x4 b) {
    asm volatile("v_mfma_f32_16x16x16_bf16 %0, %1, %2, %0"
                 : "+v"(acc) : "v"(a), "v"(b));
}
__device__ __forceinline__ v4f mfma32_z(s16x8 a, s16x8 b, v4f z) {
    v4f d;
    asm volatile("v_mfma_f32_16x16x32_bf16 %0, %2, %3, %1"
                 : "=&v"(d) : "v"(z), "v"(a), "v"(b));
    return d;
}
__device__ __forceinline__ void mfma32_acc(v4f& acc, s16x8 a, s16x8 b) {
    asm volatile("v_mfma_f32_16x16x32_bf16 %0, %1, %2, %0"
                 : "+v"(acc) : "v"(a), "v"(b));
}

// ======================= shared step/init functions =======================
// State semantics (both paths, proven r7-r10): M kept bf16 in B-frag(==C)
// layout; per step acc = E*M (f32), gn = raw P00; M' = acc .* (em*s) with
// lagged s = 1/gn_prev; Lc accumulates log2(gn) one step behind.

__device__ __forceinline__ void k16_init(s16x4 (&mw)[3][3], const v4f (&bfv)[9],
                                         const v4f (&em)[3]) {
    #pragma unroll
    for (int K = 0; K < 3; ++K)
        #pragma unroll
        for (int J = 0; J < 3; ++J) {
            v4f sc = bfv[K * 3 + J] * em[K];
            mw[K][J] = __builtin_bit_cast(s16x4,
                (u32x2){pkbf(sc.x, sc.y), pkbf(sc.z, sc.w)});
        }
}

__device__ __forceinline__ void k16_step(s16x4 (&mw)[3][3], const s16x4 (&aw)[3][3],
                                         const v4f (&em)[3],
                                         float& Lc, float& lg, float& s) {
    const v4f kz = {0.f, 0.f, 0.f, 0.f};
    v4f acc[3][3];
    #pragma unroll
    for (int I = 0; I < 3; ++I)
        #pragma unroll
        for (int J = 0; J < 3; ++J)
            acc[I][J] = mfma16_z(aw[I][0], mw[0][J], kz);
    #pragma unroll
    for (int I = 0; I < 3; ++I)
        #pragma unroll
        for (int J = 0; J < 3; ++J)
            mfma16_acc(acc[I][J], aw[I][1], mw[1][J]);
    #pragma unroll
    for (int I = 0; I < 3; ++I)
        #pragma unroll
        for (int J = 0; J < 3; ++J)
            mfma16_acc(acc[I][J], aw[I][2], mw[2][J]);
    asm volatile("s_nop 7\n\ts_nop 7");
    __builtin_amdgcn_sched_barrier(0);

    const float gn = rfl(acc[0][0].x);
    Lc += lg;
    #pragma unroll
    for (int K = 0; K < 3; ++K) {
        v4f sp = em[K] * s;
        #pragma unroll
        for (int J = 0; J < 3; ++J) {
            v4f sc = acc[K][J] * sp;
            mw[K][J] = __builtin_bit_cast(s16x4,
                (u32x2){pkbf(sc.x, sc.y), pkbf(sc.z, sc.w)});
        }
    }
    lg = __log2f(gn);
    s  = __builtin_amdgcn_rcpf(gn);
}

__device__ __forceinline__ void k32_init(u32x4 (&P)[3], u32x4 (&Q)[3],
                                         const v4f (&bfv)[9], const v4f (&em)[3]) {
    #pragma unroll
    for (int J = 0; J < 3; ++J) {
        v4f s0 = bfv[0 * 3 + J] * em[0];
        v4f s1 = bfv[1 * 3 + J] * em[1];
        v4f s2 = bfv[2 * 3 + J] * em[2];
        P[J] = (u32x4){pkbf(s0.x, s0.y), pkbf(s0.z, s0.w),
                       pkbf(s1.x, s1.y), pkbf(s1.z, s1.w)};
        u32 a2 = pkbf(s2.x, s2.y), b2 = pkbf(s2.z, s2.w);
        Q[J] = (u32x4){a2, b2, a2, b2};
    }
}

__device__ __forceinline__ void k32_step(u32x4 (&P)[3], u32x4 (&Q)[3],
                                         const s16x8 (&aw)[3][2], const v4f (&em)[3],
                                         float& Lc, float& lg, float& s) {
    const v4f kz = {0.f, 0.f, 0.f, 0.f};
    v4f acc[3][3];
    #pragma unroll
    for (int I = 0; I < 3; ++I)
        #pragma unroll
        for (int J = 0; J < 3; ++J)
            acc[I][J] = mfma32_z(aw[I][0], __builtin_bit_cast(s16x8, P[J]), kz);
    #pragma unroll
    for (int I = 0; I < 3; ++I)
        #pragma unroll
        for (int J = 0; J < 3; ++J)
            mfma32_acc(acc[I][J], aw[I][1], __builtin_bit_cast(s16x8, Q[J]));
    asm volatile("s_nop 7\n\ts_nop 7");
    __builtin_amdgcn_sched_barrier(0);

    const float gn = rfl(acc[0][0].x);
    Lc += lg;
    v4f sp0 = em[0] * s, sp1 = em[1] * s, sp2 = em[2] * s;
    #pragma unroll
    for (int J = 0; J < 3; ++J) {
        v4f s0 = acc[0][J] * sp0;
        v4f s1 = acc[1][J] * sp1;
        v4f s2 = acc[2][J] * sp2;
        P[J] = (u32x4){pkbf(s0.x, s0.y), pkbf(s0.z, s0.w),
                       pkbf(s1.x, s1.y), pkbf(s1.z, s1.w)};
        u32 a2 = pkbf(s2.x, s2.y), b2 = pkbf(s2.z, s2.w);
        Q[J] = (u32x4){a2, b2, a2, b2};
    }
    lg = __log2f(gn);
    s  = __builtin_amdgcn_rcpf(gn);
}

__device__ __forceinline__ bool near2(u32 a, u32 b) {
    float al = bflo(a), ah = bfhi(a), bl = bflo(b), bh = bfhi(b);
    bool o1 = fabsf(al - bl) <= 0.08f * fmaxf(fabsf(al), fabsf(bl)) + 1e-4f;
    bool o2 = fabsf(ah - bh) <= 0.08f * fmaxf(fabsf(ah), fabsf(bh)) + 1e-4f;
    return o1 && o2;
}

// ---------------------------------------------------------------------------
// Kernel 0: build all fragment tables, then PROBE the K32 path against the
// proven K16 path (4-step mini-chain, same shared device functions) and
// publish flag (1 = K32 validated on this hardware).
// ---------------------------------------------------------------------------
__global__ void __launch_bounds__(64)
crf_setup(const float* __restrict__ trans, void* ws) {
    __shared__ float el[NT * NT];
    const int lane = threadIdx.x, ln = lane & 15, g = lane >> 4;
    #pragma unroll
    for (int m = 0; m < 36; ++m) {
        int idx = lane + 64 * m;
        el[idx] = __expf(trans[idx]);
    }
    u32x2* AF16 = (u32x2*)((char*)ws + TAF16);
    u32x4* AW32 = (u32x4*)((char*)ws + TAF32);
    v4f*   BF   = (v4f*)((char*)ws + TBF);

    s16x4 aw16[3][3];
    s16x8 aw32[3][2];
    #pragma unroll
    for (int I = 0; I < 3; ++I) {
        u32 p[3][2];
        #pragma unroll
        for (int K = 0; K < 3; ++K) {
            const v4f ev = *(const v4f*)&el[(I * 16 + ln) * NT + K * 16 + g * 4];
            p[K][0] = pkbf(ev.x, ev.y);
            p[K][1] = pkbf(ev.z, ev.w);
            AF16[(I * 3 + K) * 64 + lane] = (u32x2){p[K][0], p[K][1]};
            aw16[I][K] = __builtin_bit_cast(s16x4, (u32x2){p[K][0], p[K][1]});
        }
        u32x4 w0 = (u32x4){p[0][0], p[0][1], p[1][0], p[1][1]};
        u32x4 w1 = (u32x4){p[2][0], p[2][1], 0u, 0u};
        AW32[(I * 2 + 0) * 64 + lane] = w0;
        AW32[(I * 2 + 1) * 64 + lane] = w1;
        aw32[I][0] = __builtin_bit_cast(s16x8, w0);
        aw32[I][1] = __builtin_bit_cast(s16x8, w1);
    }
    v4f bfv[9];
    #pragma unroll
    for (int K = 0; K < 3; ++K)
        #pragma unroll
        for (int J = 0; J < 3; ++J) {
            v4f v;
            #pragma unroll
            for (int i = 0; i < 4; ++i)
                v[i] = el[(K * 16 + g * 4 + i) * NT + J * 16 + ln];
            BF[(K * 3 + J) * 64 + lane] = v;
            bfv[K * 3 + J] = v;
        }

    // ---- probe: 4-step mini-chain K16 vs K32, synthetic positive emissions
    v4f em[3];
    auto synth = [&](int t, v4f (&e)[3]) {
        #pragma unroll
        for (int K = 0; K < 3; ++K)
            #pragma unroll
            for (int i = 0; i < 4; ++i) {
                int row = K * 16 + g * 4 + i;
                e[K][i] = el[(unsigned)(t * 131 + row * 7) % (NT * NT)] + 0.5f;
            }
    };
    s16x4 m16[3][3];
    u32x4 P[3], Q[3];
    synth(0, em);
    k16_init(m16, bfv, em);
    k32_init(P, Q, bfv, em);
    float Lc16 = 0.f, lg16 = 0.f, s16s = 1.f;
    float Lc32 = 0.f, lg32 = 0.f, s32s = 1.f;
    for (int t = 1; t <= 4; ++t) { synth(t, em); k16_step(m16, aw16, em, Lc16, lg16, s16s); }
    for (int t = 1; t <= 4; ++t) { synth(t, em); k32_step(P, Q, aw32, em, Lc32, lg32, s32s); }

    bool ok = fabsf(Lc16 - Lc32) <= 0.2f;
    #pragma unroll
    for (int J = 0; J < 3; ++J) {
        u32x2 w0 = __builtin_bit_cast(u32x2, m16[0][J]);
        u32x2 w1 = __builtin_bit_cast(u32x2, m16[1][J]);
        u32x2 w2 = __builtin_bit_cast(u32x2, m16[2][J]);
        ok = ok && near2(w0.x, P[J].x) && near2(w0.y, P[J].y);
        ok = ok && near2(w1.x, P[J].z) && near2(w1.y, P[J].w);
        ok = ok && near2(w2.x, Q[J].x) && near2(w2.y, Q[J].y);
    }
    unsigned long long vote = __ballot(ok);
    if (lane == 0)
        *((u32*)((char*)ws + TFLAG)) = (vote == 0xFFFFFFFFFFFFFFFFull) ? 1u : 0u;
}

// ---------------------------------------------------------------------------
// Kernel 1 (hybrid): one chunk (32 steps) per wave, 4 waves/WG, wave-private
// LDS.  Wave-uniform branch on the HW-probe flag: K32 fast path (18 MFMA at
// ~5cyc pipe) if validated, else the proven K16 path (27 MFMA at ~16.7cyc).
// ---------------------------------------------------------------------------
__global__ void __launch_bounds__(256, 3)
crf_phase1_hy(const float* __restrict__ feat, const int* __restrict__ seqlen,
              void* __restrict__ ws) {
    const int b = blockIdx.x;
    const int wid = threadIdx.x >> 6;
    const int c = blockIdx.y * 4 + wid;
    const int t0 = c * 32;
    const int L = seqlen[b];
    int n = L - t0;
    if (n <= 0) return;
    if (n > 32) n = 32;

    const int lane = threadIdx.x & 63, ln = lane & 15, g = lane >> 4;

    __shared__ v4f flv[4][32 * 12 + 16];
    v4f* fl = flv[wid];

    const u32 flag = *(const u32*)((const char*)ws + TFLAG);

    // stage rows t0..t0+31 (t0 <= 2016, in-bounds), exp() applied once
    {
        const v4f* fg = (const v4f*)(feat + ((size_t)b * SEQ + t0) * NT);
        #pragma unroll
        for (int m = 0; m < 6; ++m) {
            v4f v = fg[m * 64 + lane];
            v4f e;
            #pragma unroll
            for (int i = 0; i < 4; ++i) e[i] = __expf(v[i]);
            fl[m * 64 + lane] = e;
        }
    }

    v4f em[3];
    #pragma unroll
    for (int K = 0; K < 3; ++K) em[K] = fl[K * 4 + g];

    float Lc = 0.f, lg = 0.f, s = 1.f;
    char* wb = (char*)ws + TW + ((size_t)(b * 64 + c)) * 4608;
    const v4f* BF = (const v4f*)((const char*)ws + TBF);

    if (flag) {
        s16x8 aw[3][2];
        const u32x4* AW = (const u32x4*)((const char*)ws + TAF32);
        #pragma unroll
        for (int I = 0; I < 3; ++I)
            #pragma unroll
            for (int Kc = 0; Kc < 2; ++Kc)
                aw[I][Kc] = __builtin_bit_cast(s16x8, AW[(I * 2 + Kc) * 64 + lane]);
        u32x4 P[3], Q[3];
        {
            v4f bfv[9];
            #pragma unroll
            for (int q = 0; q < 9; ++q) bfv[q] = BF[q * 64 + lane];
            k32_init(P, Q, bfv, em);
        }
        for (int t = 1; t < n; ++t) {
            #pragma unroll
            for (int K = 0; K < 3; ++K) em[K] = fl[t * 12 + K * 4 + g];
            k32_step(P, Q, aw, em, Lc, lg, s);
        }
        #pragma unroll
        for (int J = 0; J < 3; ++J) {
            const int base = (J * 16 + ln) * NT + g * 4;
            *(u32*)(wb + 2 * (base))          = P[J].x;
            *(u32*)(wb + 2 * (base + 2))      = P[J].y;
            *(u32*)(wb + 2 * (base + 16))     = P[J].z;
            *(u32*)(wb + 2 * (base + 16 + 2)) = P[J].w;
            *(u32*)(wb + 2 * (base + 32))     = Q[J].x;
            *(u32*)(wb + 2 * (base + 32 + 2)) = Q[J].y;
        }
    } else {
        s16x4 aw[3][3];
        const u32x2* AF = (const u32x2*)((const char*)ws + TAF16);
        #pragma unroll
        for (int I = 0; I < 3; ++I)
            #pragma unroll
            for (int K = 0; K < 3; ++K)
                aw[I][K] = __builtin_bit_cast(s16x4, AF[(I * 3 + K) * 64 + lane]);
        s16x4 mw[3][3];
        {
            v4f bfv[9];
            #pragma unroll
            for (int q = 0; q < 9; ++q) bfv[q] = BF[q * 64 + lane];
            k16_init(mw, bfv, em);
        }
        for (int t = 1; t < n; ++t) {
            #pragma unroll
            for (int K = 0; K < 3; ++K) em[K] = fl[t * 12 + K * 4 + g];
            k16_step(mw, aw, em, Lc, lg, s);
        }
        #pragma unroll
        for (int K = 0; K < 3; ++K)
            #pragma unroll
            for (int J = 0; J < 3; ++J) {
                u32x2 w = __builtin_bit_cast(u32x2, mw[K][J]);
                *(u32*)(wb + 2 * ((J * 16 + ln) * NT + K * 16 + g * 4))     = w.x;
                *(u32*)(wb + 2 * ((J * 16 + ln) * NT + K * 16 + g * 4 + 2)) = w.y;
            }
    }
    if (lane == 0)
        ((float*)((char*)ws + TSC))[b * 64 + c] = Lc;
}

// ---------------------------------------------------------------------------
// Kernel 2: per sample, u^T <- u^T * M_c for c = nb-1..0; lane j owns u[j];
// M^T row j contiguous bf16; next chunk's row double-buffered.
// ---------------------------------------------------------------------------
__global__ void __launch_bounds__(64)
crf_phase2(const float* __restrict__ trans, const int* __restrict__ seqlen,
           const void* __restrict__ ws, float* __restrict__ out) {
    const int b = blockIdx.x;
    const int lane = threadIdx.x;
    const int j = (lane < NT) ? lane : (lane - 16);
    __shared__ v4f hs4[12];
    float* hs = (float*)hs4;

    const int L = seqlen[b];
    const int nb = (L + 31) / 32;
    const float* sc = (const float*)((const char*)ws + TSC) + b * 64;
    const char* wbase = (const char*)ws + TW + (size_t)b * 64 * 4608;

    float q = __expf(trans[END_TAG * NT + j]);   // u0 (exp(MIN)=0 -> col END)
    float D = 0.f;

    u32x4 buf[6];
    {
        const u32x4* wr = (const u32x4*)(wbase + (size_t)(nb - 1) * 4608 + j * 96);
        #pragma unroll
        for (int m = 0; m < 6; ++m) buf[m] = wr[m];
    }

    for (int c = nb - 1; c >= 0; --c) {
        u32x4 cur[6];
        #pragma unroll
        for (int m = 0; m < 6; ++m) cur[m] = buf[m];
        if (c > 0) {
            const u32x4* wr = (const u32x4*)(wbase + (size_t)(c - 1) * 4608 + j * 96);
            #pragma unroll
            for (int m = 0; m < 6; ++m) buf[m] = wr[m];
        }

        if (lane < NT) hs[lane] = q;
        v4f hq[12];
        #pragma unroll
        for (int k = 0; k < 12; ++k) hq[k] = hs4[k];
        const float h0 = hq[0][0];

        v2f a = {0.f, 0.f};
        #pragma unroll
        for (int m = 0; m < 6; ++m) {
            #pragma unroll
            for (int p = 0; p < 4; ++p) {
                const int i = 2 * (4 * m + p);
                u32 wv = cur[m][p];
                v2f wp;
                wp.x = bflo(wv);
                wp.y = bfhi(wv);
                v2f up = { hq[i >> 2][i & 3], hq[i >> 2][(i & 3) + 1] };
                a += wp * up;
            }
        }
        const float dot = a.x + a.y;
        q = dot * __builtin_amdgcn_rcpf(h0);
        D += __log2f(h0) + sc[c];
    }
    if (lane < NT) hs[lane] = q;
    if (lane == 0)
        out[b] = LN2f * (D + __log2f(hs[START_TAG]));
}

// ---------------------------------------------------------------------------
// Fallback: proven round-2 scalar kernel (ws too small)
// ---------------------------------------------------------------------------
__global__ void __launch_bounds__(64)
crf_scalar(const float* __restrict__ features, const float* __restrict__ transitions,
           const int* __restrict__ seq_len, float* __restrict__ out) {
    const int b = blockIdx.x;
    const int lane = threadIdx.x;
    const int j = (lane < NT) ? lane : (lane - 16);
    __shared__ v4f hs4[NT / 4];
    float* hs = (float*)hs4;

    v2f E2[NT / 2];
    {
        const v4f* trow = (const v4f*)(transitions + j * NT);
        #pragma unroll
        for (int k = 0; k < NT / 4; ++k) {
            v4f tv = trow[k];
            E2[2 * k].x = __expf(tv.x); E2[2 * k].y = __expf(tv.y);
            E2[2 * k + 1].x = __expf(tv.z); E2[2 * k + 1].y = __expf(tv.w);
        }
    }
    const float Eend = __expf(transitions[END_TAG * NT + j]);
    const int L = seq_len[b];
    const float* fbase = features + ((size_t)b * SEQ) * NT + j;

    float q = E2[START_TAG / 2].x * __expf(fbase[0]);
    float Clog2 = 0.0f;
    if (lane < NT) hs[lane] = q;

    float fb[8];
    #pragma unroll
    for (int u = 0; u < 8; ++u) {
        int tp = 1 + u;
        fb[u] = fbase[(size_t)(tp < SEQ ? tp : 0) * NT];
    }

    auto STEP = [&](float femit) {
        v4f hq[NT / 4];
        #pragma unroll
        for (int k = 0; k < NT / 4; ++k) hq[k] = hs4[k];
        float h0 = hq[0].x;
        float r = __builtin_amdgcn_rcpf(h0);
        float e = __expf(femit);
        float re = r * e;
        v2f a0 = {0.f, 0.f}, a1 = {0.f, 0.f};
        #pragma unroll
        for (int k = 0; k < NT / 4; ++k) {
            v2f lo = { hq[k].x, hq[k].y };
            v2f hi = { hq[k].z, hq[k].w };
            a0 += E2[2 * k] * lo;
            a1 += E2[2 * k + 1] * hi;
        }
        float d = (a0.x + a1.x) + (a0.y + a1.y);
        q = d * re;
        Clog2 += __log2f(h0);
        if (lane < NT) hs[lane] = q;
    };

    int t = 1;
    while (t + 8 <= L) {
        #pragma unroll
        for (int u = 0; u < 8; ++u) {
            STEP(fb[u]);
            int tp = t + u + 8;
            fb[u] = fbase[(size_t)(tp < SEQ ? tp : 0) * NT];
        }
        t += 8;
    }
    #pragma unroll
    for (int u = 0; u < 8; ++u)
        if (t + u < L) STEP(fb[u]);

    float term = (lane < NT) ? q * Eend : 0.0f;
    #pragma unroll
    for (int m = 32; m >= 1; m >>= 1) term += __shfl_xor(term, m, 64);
    if (lane == 0) out[b] = LN2f * (Clog2 + __log2f(term));
}

extern "C" void kernel_launch(void* const* d_in, const int* in_sizes, int n_in,
                              void* d_out, int out_size, void* d_ws, size_t ws_size,
                              hipStream_t stream) {
    const float* features    = (const float*)d_in[0];
    const float* transitions = (const float*)d_in[1];
    const int*   seqlen      = (const int*)d_in[2];
    float* out = (float*)d_out;

    const size_t need = (size_t)TW + (size_t)BATCH * 64 * 4608;   // ~75.6 MB
    if (ws_size >= need) {
        crf_setup<<<1, 64, 0, stream>>>(transitions, d_ws);
        crf_phase1_hy<<<dim3(BATCH, 16), 256, 0, stream>>>(features, seqlen, d_ws);
        crf_phase2<<<BATCH, 64, 0, stream>>>(transitions, seqlen, d_ws, out);
    } else {
        crf_scalar<<<BATCH, 64, 0, stream>>>(features, transitions, seqlen, out);
    }
}

// Round 13
// 130.529 us; speedup vs baseline: 1.2499x; 1.2066x over previous
//
#include <hip/hip_runtime.h>

#define BATCH 256
#define SEQ 2048
#define NT 48
#define START_TAG 46
#define END_TAG 47
#define LN2f  0.6931471805599453f

// ws layout
#define TAF16 0        // K16 A-frags exp(trans) bf16: [9][64] x 8B  = 4608
#define TBF   4608     // B-frag exp(trans) f32: [9][64] x 16B       = 9216
#define TCUM  13824    // prefix sums: int cum[257] (cum[0]=0)       = 1028
#define TSC   16384    // per-chunk log2 scales: [B][64] f32         = 65536
#define TW    131072   // chunk matrices M^T bf16: [B][64][48][48]

typedef float v2f __attribute__((ext_vector_type(2)));
typedef float v4f __attribute__((ext_vector_type(4)));
typedef short s16x4 __attribute__((ext_vector_type(4)));
typedef unsigned int u32;
typedef u32 u32x2 __attribute__((ext_vector_type(2)));
typedef u32 u32x4 __attribute__((ext_vector_type(4)));

__device__ __forceinline__ u32 pkbf(float a, float b) {
    u32 r;
    asm("v_cvt_pk_bf16_f32 %0, %1, %2" : "=v"(r) : "v"(a), "v"(b));
    return r;
}
__device__ __forceinline__ float bflo(u32 w) { return __builtin_bit_cast(float, w << 16); }
__device__ __forceinline__ float bfhi(u32 w) { return __builtin_bit_cast(float, w & 0xffff0000u); }

__device__ __forceinline__ float rfl(float x) {
    return __builtin_bit_cast(float,
        __builtin_amdgcn_readfirstlane(__builtin_bit_cast(int, x)));
}

__device__ __forceinline__ v4f mfma16_z(s16x4 a, s16x4 b, v4f z) {
    v4f d;
    asm volatile("v_mfma_f32_16x16x16_bf16 %0, %2, %3, %1"
                 : "=&v"(d) : "v"(z), "v"(a), "v"(b));
    return d;
}
__device__ __forceinline__ void mfma16_acc(v4f& acc, s16x4 a, s16x4 b) {
    asm volatile("v_mfma_f32_16x16x16_bf16 %0, %1, %2, %0"
                 : "+v"(acc) : "v"(a), "v"(b));
}

// ---------------------------------------------------------------------------
// Kernel 0: build exp(trans) fragments + per-sample chunk-count prefix sums.
// A-frag (tile I,K): lane holds E[I*16+(l&15)][K*16+(l>>4)*4+i], bf16.
// B-frag (tile K,J): lane holds E[K*16+(l>>4)*4+i][J*16+(l&15)], f32.
// cum[b] = sum_{b'<b} ceil(L[b']/32); cum[BATCH] = total active chunks.
// ---------------------------------------------------------------------------
__global__ void __launch_bounds__(64)
crf_setup(const float* __restrict__ trans, const int* __restrict__ seqlen,
          void* ws) {
    __shared__ float el[NT * NT];
    const int lane = threadIdx.x, ln = lane & 15, g = lane >> 4;
    #pragma unroll
    for (int m = 0; m < 36; ++m) {
        int idx = lane + 64 * m;
        el[idx] = __expf(trans[idx]);
    }
    u32x2* AF = (u32x2*)((char*)ws + TAF16);
    v4f*   BF = (v4f*)((char*)ws + TBF);
    #pragma unroll
    for (int I = 0; I < 3; ++I)
        #pragma unroll
        for (int K = 0; K < 3; ++K) {
            const v4f ev = *(const v4f*)&el[(I * 16 + ln) * NT + K * 16 + g * 4];
            AF[(I * 3 + K) * 64 + lane] = (u32x2){pkbf(ev.x, ev.y), pkbf(ev.z, ev.w)};
        }
    #pragma unroll
    for (int K = 0; K < 3; ++K)
        #pragma unroll
        for (int J = 0; J < 3; ++J) {
            v4f v;
            #pragma unroll
            for (int i = 0; i < 4; ++i)
                v[i] = el[(K * 16 + g * 4 + i) * NT + J * 16 + ln];
            BF[(K * 3 + J) * 64 + lane] = v;
        }
    // prefix sum of chunk counts (tiny; lane 0 serial)
    if (lane == 0) {
        int* cum = (int*)((char*)ws + TCUM);
        int acc = 0;
        for (int b = 0; b < BATCH; ++b) {
            cum[b] = acc;
            int L = seqlen[b];
            if (L < 1) L = 1;
            if (L > SEQ) L = SEQ;
            acc += (L + 31) >> 5;
        }
        cum[BATCH] = acc;
    }
}

// ---------------------------------------------------------------------------
// Kernel 1 (compacted): wave widx = 4*blockIdx.x + wid handles the widx-th
// ACTIVE chunk (binary search over cum[]).  Dead waves exist only past the
// end of the compacted range -> resident wave slots hold live work.
// Per chunk: 32-step K16 MFMA chain (r12-proven math): acc = E*M (27 MFMA,
// 3 levels x 9, asm-pinned), gn = raw P00, M' = acc .* (em * 1/gn_prev),
// Lc += log2(gn) lagged.  Emissions pre-exp'd into wave-private LDS.
// __launch_bounds__(256,4): 4 WG/CU (LDS 100KiB, VGPR<=128) -> up to
// 4 live waves/SIMD vs r12's 1.6 (the occupancy experiment).
// ---------------------------------------------------------------------------
__global__ void __launch_bounds__(256, 4)
crf_phase1c(const float* __restrict__ feat, const int* __restrict__ seqlen,
            void* __restrict__ ws) {
    const int wid = threadIdx.x >> 6;
    const int widx = blockIdx.x * 4 + wid;
    const int* cum = (const int*)((const char*)ws + TCUM);
    if (widx >= cum[BATCH]) return;

    // binary search: largest b with cum[b] <= widx
    int lo = 0, hi = BATCH;          // invariant: cum[lo] <= widx < cum[hi]
    #pragma unroll
    for (int it = 0; it < 8; ++it) {
        int mid = (lo + hi) >> 1;
        if (cum[mid] <= widx) lo = mid; else hi = mid;
    }
    const int b = lo;
    const int c = widx - cum[b];
    const int t0 = c * 32;
    const int L = seqlen[b];
    int n = L - t0;
    if (n > 32) n = 32;

    const int lane = threadIdx.x & 63, ln = lane & 15, g = lane >> 4;

    __shared__ v4f flv[4][32 * 12 + 16];
    v4f* fl = flv[wid];

    s16x4 aw[3][3];
    {
        const u32x2* AF = (const u32x2*)((const char*)ws + TAF16);
        #pragma unroll
        for (int I = 0; I < 3; ++I)
            #pragma unroll
            for (int K = 0; K < 3; ++K)
                aw[I][K] = __builtin_bit_cast(s16x4, AF[(I * 3 + K) * 64 + lane]);
    }

    // stage rows t0..t0+31 (t0 <= 2016, in-bounds), exp() applied once
    {
        const v4f* fg = (const v4f*)(feat + ((size_t)b * SEQ + t0) * NT);
        #pragma unroll
        for (int m = 0; m < 6; ++m) {
            v4f v = fg[m * 64 + lane];
            v4f e;
            #pragma unroll
            for (int i = 0; i < 4; ++i) e[i] = __expf(v[i]);
            fl[m * 64 + lane] = e;
        }
    }

    // init M = D_{t0} E
    s16x4 mw[3][3];
    {
        const v4f* BF = (const v4f*)((const char*)ws + TBF);
        v4f em[3];
        #pragma unroll
        for (int K = 0; K < 3; ++K) em[K] = fl[K * 4 + g];
        #pragma unroll
        for (int K = 0; K < 3; ++K)
            #pragma unroll
            for (int J = 0; J < 3; ++J) {
                v4f sc = BF[(K * 3 + J) * 64 + lane] * em[K];
                mw[K][J] = __builtin_bit_cast(s16x4,
                    (u32x2){pkbf(sc.x, sc.y), pkbf(sc.z, sc.w)});
            }
    }

    float Lc = 0.f, lg = 0.f, s = 1.f;
    const v4f kz = {0.f, 0.f, 0.f, 0.f};

    for (int t = 1; t < n; ++t) {
        v4f em[3];
        #pragma unroll
        for (int K = 0; K < 3; ++K) em[K] = fl[t * 12 + K * 4 + g];

        v4f acc[3][3];
        #pragma unroll
        for (int I = 0; I < 3; ++I)
            #pragma unroll
            for (int J = 0; J < 3; ++J)
                acc[I][J] = mfma16_z(aw[I][0], mw[0][J], kz);
        #pragma unroll
        for (int I = 0; I < 3; ++I)
            #pragma unroll
            for (int J = 0; J < 3; ++J)
                mfma16_acc(acc[I][J], aw[I][1], mw[1][J]);
        #pragma unroll
        for (int I = 0; I < 3; ++I)
            #pragma unroll
            for (int J = 0; J < 3; ++J)
                mfma16_acc(acc[I][J], aw[I][2], mw[2][J]);
        asm volatile("s_nop 7\n\ts_nop 7");
        __builtin_amdgcn_sched_barrier(0);

        const float gn = rfl(acc[0][0].x);
        Lc += lg;
        #pragma unroll
        for (int K = 0; K < 3; ++K) {
            v4f sp = em[K] * s;
            #pragma unroll
            for (int J = 0; J < 3; ++J) {
                v4f sc = acc[K][J] * sp;
                mw[K][J] = __builtin_bit_cast(s16x4,
                    (u32x2){pkbf(sc.x, sc.y), pkbf(sc.z, sc.w)});
            }
        }
        lg = __log2f(gn);
        s  = __builtin_amdgcn_rcpf(gn);
    }

    // store M^T bf16 (element M[kk][nn] -> byte 2*(nn*48+kk)) + scale
    char* wb = (char*)ws + TW + ((size_t)(b * 64 + c)) * 4608;
    #pragma unroll
    for (int K = 0; K < 3; ++K)
        #pragma unroll
        for (int J = 0; J < 3; ++J) {
            u32x2 w = __builtin_bit_cast(u32x2, mw[K][J]);
            *(u32*)(wb + 2 * ((J * 16 + ln) * NT + K * 16 + g * 4))     = w.x;
            *(u32*)(wb + 2 * ((J * 16 + ln) * NT + K * 16 + g * 4 + 2)) = w.y;
        }
    if (lane == 0)
        ((float*)((char*)ws + TSC))[b * 64 + c] = Lc;
}

// ---------------------------------------------------------------------------
// Kernel 2: per sample, u^T <- u^T * M_c for c = nb-1..0; lane j owns u[j];
// M^T row j contiguous bf16; next chunk's row double-buffered.
// ---------------------------------------------------------------------------
__global__ void __launch_bounds__(64)
crf_phase2(const float* __restrict__ trans, const int* __restrict__ seqlen,
           const void* __restrict__ ws, float* __restrict__ out) {
    const int b = blockIdx.x;
    const int lane = threadIdx.x;
    const int j = (lane < NT) ? lane : (lane - 16);
    __shared__ v4f hs4[12];
    float* hs = (float*)hs4;

    const int L = seqlen[b];
    const int nb = (L + 31) / 32;
    const float* sc = (const float*)((const char*)ws + TSC) + b * 64;
    const char* wbase = (const char*)ws + TW + (size_t)b * 64 * 4608;

    float q = __expf(trans[END_TAG * NT + j]);   // u0 (exp(MIN)=0 -> col END)
    float D = 0.f;

    u32x4 buf[6];
    {
        const u32x4* wr = (const u32x4*)(wbase + (size_t)(nb - 1) * 4608 + j * 96);
        #pragma unroll
        for (int m = 0; m < 6; ++m) buf[m] = wr[m];
    }

    for (int c = nb - 1; c >= 0; --c) {
        u32x4 cur[6];
        #pragma unroll
        for (int m = 0; m < 6; ++m) cur[m] = buf[m];
        if (c > 0) {
            const u32x4* wr = (const u32x4*)(wbase + (size_t)(c - 1) * 4608 + j * 96);
            #pragma unroll
            for (int m = 0; m < 6; ++m) buf[m] = wr[m];
        }

        if (lane < NT) hs[lane] = q;
        v4f hq[12];
        #pragma unroll
        for (int k = 0; k < 12; ++k) hq[k] = hs4[k];
        const float h0 = hq[0][0];

        v2f a = {0.f, 0.f};
        #pragma unroll
        for (int m = 0; m < 6; ++m) {
            #pragma unroll
            for (int p = 0; p < 4; ++p) {
                const int i = 2 * (4 * m + p);
                u32 wv = cur[m][p];
                v2f wp;
                wp.x = bflo(wv);
                wp.y = bfhi(wv);
                v2f up = { hq[i >> 2][i & 3], hq[i >> 2][(i & 3) + 1] };
                a += wp * up;
            }
        }
        const float dot = a.x + a.y;
        q = dot * __builtin_amdgcn_rcpf(h0);
        D += __log2f(h0) + sc[c];
    }
    if (lane < NT) hs[lane] = q;
    if (lane == 0)
        out[b] = LN2f * (D + __log2f(hs[START_TAG]));
}

// ---------------------------------------------------------------------------
// Fallback: proven round-2 scalar kernel (ws too small)
// ---------------------------------------------------------------------------
__global__ void __launch_bounds__(64)
crf_scalar(const float* __restrict__ features, const float* __restrict__ transitions,
           const int* __restrict__ seq_len, float* __restrict__ out) {
    const int b = blockIdx.x;
    const int lane = threadIdx.x;
    const int j = (lane < NT) ? lane : (lane - 16);
    __shared__ v4f hs4[NT / 4];
    float* hs = (float*)hs4;

    v2f E2[NT / 2];
    {
        const v4f* trow = (const v4f*)(transitions + j * NT);
        #pragma unroll
        for (int k = 0; k < NT / 4; ++k) {
            v4f tv = trow[k];
            E2[2 * k].x = __expf(tv.x); E2[2 * k].y = __expf(tv.y);
            E2[2 * k + 1].x = __expf(tv.z); E2[2 * k + 1].y = __expf(tv.w);
        }
    }
    const float Eend = __expf(transitions[END_TAG * NT + j]);
    const int L = seq_len[b];
    const float* fbase = features + ((size_t)b * SEQ) * NT + j;

    float q = E2[START_TAG / 2].x * __expf(fbase[0]);
    float Clog2 = 0.0f;
    if (lane < NT) hs[lane] = q;

    float fb[8];
    #pragma unroll
    for (int u = 0; u < 8; ++u) {
        int tp = 1 + u;
        fb[u] = fbase[(size_t)(tp < SEQ ? tp : 0) * NT];
    }

    auto STEP = [&](float femit) {
        v4f hq[NT / 4];
        #pragma unroll
        for (int k = 0; k < NT / 4; ++k) hq[k] = hs4[k];
        float h0 = hq[0].x;
        float r = __builtin_amdgcn_rcpf(h0);
        float e = __expf(femit);
        float re = r * e;
        v2f a0 = {0.f, 0.f}, a1 = {0.f, 0.f};
        #pragma unroll
        for (int k = 0; k < NT / 4; ++k) {
            v2f lo = { hq[k].x, hq[k].y };
            v2f hi = { hq[k].z, hq[k].w };
            a0 += E2[2 * k] * lo;
            a1 += E2[2 * k + 1] * hi;
        }
        float d = (a0.x + a1.x) + (a0.y + a1.y);
        q = d * re;
        Clog2 += __log2f(h0);
        if (lane < NT) hs[lane] = q;
    };

    int t = 1;
    while (t + 8 <= L) {
        #pragma unroll
        for (int u = 0; u < 8; ++u) {
            STEP(fb[u]);
            int tp = t + u + 8;
            fb[u] = fbase[(size_t)(tp < SEQ ? tp : 0) * NT];
        }
        t += 8;
    }
    #pragma unroll
    for (int u = 0; u < 8; ++u)
        if (t + u < L) STEP(fb[u]);

    float term = (lane < NT) ? q * Eend : 0.0f;
    #pragma unroll
    for (int m = 32; m >= 1; m >>= 1) term += __shfl_xor(term, m, 64);
    if (lane == 0) out[b] = LN2f * (Clog2 + __log2f(term));
}

extern "C" void kernel_launch(void* const* d_in, const int* in_sizes, int n_in,
                              void* d_out, int out_size, void* d_ws, size_t ws_size,
                              hipStream_t stream) {
    const float* features    = (const float*)d_in[0];
    const float* transitions = (const float*)d_in[1];
    const int*   seqlen      = (const int*)d_in[2];
    float* out = (float*)d_out;

    const size_t need = (size_t)TW + (size_t)BATCH * 64 * 4608;   // ~75.6 MB
    if (ws_size >= need) {
        crf_setup<<<1, 64, 0, stream>>>(transitions, seqlen, d_ws);
        // worst case: 256 samples x 64 chunks = 16384 waves = 4096 WGs;
        // compaction puts all dead waves past cum[BATCH] (instant exit).
        crf_phase1c<<<4096, 256, 0, stream>>>(features, seqlen, d_ws);
        crf_phase2<<<BATCH, 64, 0, stream>>>(transitions, seqlen, d_ws, out);
    } else {
        crf_scalar<<<BATCH, 64, 0, stream>>>(features, transitions, seqlen, out);
    }
}